// Round 8
// baseline (103.052 us; speedup 1.0000x reference)
//
#include <hip/hip_runtime.h>

#define Bb 4
#define AT 384
#define NBR 24
#define FEAT 128
#define ROWQ (FEAT / 4)              // 32 float4 per feature row
#define TILEQ (NBR * ROWQ)           // 768 float4 per (b,a,j) tile / (b,a) panel
#define NTILES (Bb * AT * NBR)       // 36864
#define OUTQ ((unsigned)NTILES * TILEQ)  // 28,311,552 float4

typedef float vfloat4 __attribute__((ext_vector_type(4)));

// ---------------- Kernel A: mask precompute (proven in R4) ----------------
__global__ __launch_bounds__(256) void mask_kernel(
    const int*   __restrict__ nbr,    // (B, AT, NBR)
    const float* __restrict__ cell,   // (B, AT, NBR, 3)
    unsigned int* __restrict__ ws)    // (B*AT*NBR) mask words
{
    const int ba = blockIdx.x;
    const int b  = ba / AT;
    const int t  = threadIdx.x;

    __shared__ int   s_nbr[NBR];
    __shared__ float s_cell[NBR][3];
    __shared__ int   s_nbrj[NBR][NBR];
    __shared__ float s_cellj[NBR][NBR][3];
    __shared__ int   s_mask[NBR * NBR];

    if (t < NBR) {
        s_nbr[t]     = nbr[ba * NBR + t];
        s_cell[t][0] = cell[(ba * NBR + t) * 3 + 0];
        s_cell[t][1] = cell[(ba * NBR + t) * 3 + 1];
        s_cell[t][2] = cell[(ba * NBR + t) * 3 + 2];
    }
    __syncthreads();

    for (int q = t; q < NBR * NBR; q += 256) {
        const int j = q / NBR;
        const int k = q % NBR;
        const int base = (b * AT + s_nbr[j]) * NBR + k;
        s_nbrj[j][k]     = nbr[base];
        s_cellj[j][k][0] = cell[base * 3 + 0];
        s_cellj[j][k][1] = cell[base * 3 + 1];
        s_cellj[j][k][2] = cell[base * 3 + 2];
    }
    __syncthreads();

    for (int p = t; p < NBR * NBR; p += 256) {
        const int j = p / NBR;
        const int i = p % NBR;
        int m = 0;
        if (i != j) {
            const int   myidx = s_nbr[i];
            const float c0 = s_cell[i][0];
            const float c1 = s_cell[i][1];
            const float c2 = s_cell[i][2];
            #pragma unroll
            for (int k = 0; k < NBR; ++k) {
                if (s_nbrj[j][k] == myidx &&
                    s_cellj[j][k][0] == c0 &&
                    s_cellj[j][k][1] == c1 &&
                    s_cellj[j][k][2] == c2) { m = 1; }
            }
        }
        s_mask[p] = m;
    }
    __syncthreads();

    if (t < NBR) {
        unsigned int w = 0;
        #pragma unroll
        for (int i = 0; i < NBR; ++i)
            w |= (unsigned int)s_mask[t * NBR + i] << i;
        ws[ba * NBR + t] = w;
    }
}

// ---------------- Kernel B: flat grid-stride masked fill ----------------
// Structurally identical to rocclr fillBuffer: flat float4 index space,
// grid-stride loop, no barriers, no LDS. Per iteration the tile id is
// wave-uniform (768 = 12*64 float4 per tile), so the mask word is one
// scalar L2-hit load and all branches are wave-uniform.
__global__ __launch_bounds__(256) void store_kernel(
    const vfloat4* __restrict__ edge,       // (B, AT, NBR, FEAT) as float4
    const unsigned int* __restrict__ ws,    // mask words per (b,a,j)
    vfloat4*       __restrict__ out)        // flat output
{
    const vfloat4 zero = (vfloat4)(0.f);
    const unsigned stride = gridDim.x * 256u;
    unsigned q = blockIdx.x * 256u + threadIdx.x;

    for (; q < OUTQ; q += stride) {
        const unsigned tile   = q / TILEQ;            // wave-uniform
        const unsigned within = q - tile * TILEQ;     // [0, 768)
        const unsigned w = __builtin_amdgcn_readfirstlane(ws[tile]);
        vfloat4 v = zero;
        if (w) {                                      // uniform branch (rare)
            const unsigned i = within >> 5;
            if ((w >> i) & 1u) {
                const unsigned ba = tile / NBR;       // wave-uniform
                v = edge[(size_t)ba * TILEQ + within];
            }
        }
        out[q] = v;
    }
}

// ---------------- Fallback (ws too small): R1 monolithic ----------------
__global__ __launch_bounds__(256) void mono_kernel(
    const float* __restrict__ edge,
    const int*   __restrict__ nbr,
    const float* __restrict__ cell,
    float*       __restrict__ out)
{
    const int blk = blockIdx.x;
    const int j   = blk % NBR;
    const int ba  = blk / NBR;
    const int b   = ba / AT;

    __shared__ int   s_nbrj[NBR];
    __shared__ float s_cellj[NBR][3];
    __shared__ int   s_mask[NBR];

    const int t = threadIdx.x;
    const int jatom = nbr[ba * NBR + j];

    if (t < NBR) {
        const int base = (b * AT + jatom) * NBR + t;
        s_nbrj[t]     = nbr[base];
        s_cellj[t][0] = cell[base * 3 + 0];
        s_cellj[t][1] = cell[base * 3 + 1];
        s_cellj[t][2] = cell[base * 3 + 2];
    }
    __syncthreads();

    if (t < NBR) {
        int m = 0;
        if (t != j) {
            const int   myidx = nbr[ba * NBR + t];
            const float c0 = cell[(ba * NBR + t) * 3 + 0];
            const float c1 = cell[(ba * NBR + t) * 3 + 1];
            const float c2 = cell[(ba * NBR + t) * 3 + 2];
            #pragma unroll
            for (int k = 0; k < NBR; ++k) {
                if (s_nbrj[k] == myidx &&
                    s_cellj[k][0] == c0 &&
                    s_cellj[k][1] == c1 &&
                    s_cellj[k][2] == c2) { m = 1; }
            }
        }
        s_mask[t] = m;
    }
    __syncthreads();

    const float4* __restrict__ erow = (const float4*)(edge + (size_t)ba * NBR * FEAT);
    float4*       __restrict__ orow = (float4*)(out + (size_t)blk * NBR * FEAT);
    const float4 zero = make_float4(0.f, 0.f, 0.f, 0.f);
    #pragma unroll
    for (int it = 0; it < 3; ++it) {
        const int q = t + it * 256;
        const int i = q >> 5;
        float4 v = zero;
        if (s_mask[i]) v = erow[q];
        orow[q] = v;
    }
}

extern "C" void kernel_launch(void* const* d_in, const int* in_sizes, int n_in,
                              void* d_out, int out_size, void* d_ws, size_t ws_size,
                              hipStream_t stream) {
    const float* edge = (const float*)d_in[0];
    const int*   nbr  = (const int*)d_in[1];
    const float* cell = (const float*)d_in[2];
    float*       out  = (float*)d_out;

    const size_t need = (size_t)NTILES * sizeof(unsigned int);  // 147 KB
    if (ws_size >= need) {
        unsigned int* ws = (unsigned int*)d_ws;
        mask_kernel<<<Bb * AT, 256, 0, stream>>>(nbr, cell, ws);
        store_kernel<<<2048, 256, 0, stream>>>((const vfloat4*)edge, ws,
                                               (vfloat4*)out);
    } else {
        mono_kernel<<<NTILES, 256, 0, stream>>>(edge, nbr, cell, out);
    }
}